// Round 1
// baseline (35.805 us; speedup 1.0000x reference)
//
#include <hip/hip_runtime.h>
#include <hip/hip_bf16.h>

// CSPN step: out[b,y,x] = sum_{i,j} gw[b, i*3+j, y+1, x+1] * src[y+1-i, x+1-j]
// src = h0 for center tap (i=j=1), hn otherwise; zero outside [0,H)x[0,W).

constexpr int B = 8;
constexpr int H = 352;
constexpr int W = 1216;
constexpr int HP = H + 2;   // 354
constexpr int WP = W + 2;   // 1218

__global__ __launch_bounds__(256) void cspn_kernel(
    const float* __restrict__ gw,   // [B, 9, HP, WP]
    const float* __restrict__ hn,   // [B, 1, H, W]
    const float* __restrict__ h0,   // [B, 1, H, W]
    float* __restrict__ out)        // [B, 1, H, W]
{
    int idx = blockIdx.x * blockDim.x + threadIdx.x;
    constexpr int total = B * H * W;
    if (idx >= total) return;

    int x = idx % W;
    int t2 = idx / W;
    int y = t2 % H;
    int b = t2 / H;

    const float* gwb = gw + (size_t)b * 9 * HP * WP + (size_t)(y + 1) * WP + (x + 1);
    const float* hnb = hn + (size_t)b * H * W;
    const float* h0b = h0 + (size_t)b * H * W;

    float acc = 0.0f;
#pragma unroll
    for (int i = 0; i < 3; ++i) {
        int yy = y + 1 - i;
        bool yin = (yy >= 0) & (yy < H);
#pragma unroll
        for (int j = 0; j < 3; ++j) {
            const int t = i * 3 + j;
            int xx = x + 1 - j;
            bool in = yin & (xx >= 0) & (xx < W);
            float s = 0.0f;
            if (in) {
                const float* src = (t == 4) ? h0b : hnb;
                s = src[(size_t)yy * W + xx];
            }
            acc += gwb[(size_t)t * HP * WP] * s;
        }
    }
    out[idx] = acc;
}

extern "C" void kernel_launch(void* const* d_in, const int* in_sizes, int n_in,
                              void* d_out, int out_size, void* d_ws, size_t ws_size,
                              hipStream_t stream) {
    const float* gw = (const float*)d_in[0];
    const float* hn = (const float*)d_in[1];
    const float* h0 = (const float*)d_in[2];
    float* out = (float*)d_out;

    constexpr int total = B * H * W;
    constexpr int block = 256;
    int grid = (total + block - 1) / block;
    cspn_kernel<<<grid, block, 0, stream>>>(gw, hn, h0, out);
}